// Round 7
// baseline (124.133 us; speedup 1.0000x reference)
//
#include <hip/hip_runtime.h>
#include <stdint.h>

// Segmented top-4 over CSR (N=500K segments, E=32M edges).
// d_out = f32: [N*4 topk_vals][N*4 topk_idx-as-float], 16 MB.
// Pads MUST be bf16-finite (checker compares in bf16; -inf pad => nan).
//
// One 64-lane wave = 4 segments x 16 lanes. Each lane keeps a branchless
// sorted top-4 (monotone u64 keys) of its aligned float4-strided slice;
// 4-stage xor-butterfly bitonic merge combines the 16 lanes; lane 0 packs
// two float4 stores. Key: hi32 = order-preserving f32 bits (desc score),
// lo32 = ~edge_idx  ==  jnp.lexsort((-scores, seg)) semantics exactly.

typedef unsigned long long u64;

__device__ __forceinline__ u64 bfly(u64 x, int m) {
  unsigned lo = __shfl_xor((unsigned)x, m, 64);
  unsigned hi = __shfl_xor((unsigned)(x >> 32), m, 64);
  return ((u64)hi << 32) | (u64)lo;
}

__device__ __forceinline__ u64 mkkey(float f, int p) {
  uint32_t b = __float_as_uint(f);
  uint32_t flip = ((uint32_t)(((int32_t)b) >> 31)) | 0x80000000u;  // branchless
  return ((u64)(b ^ flip) << 32) | (u64)(~(uint32_t)p);
}

// Branchless sorted insert into a0 >= a1 >= a2 >= a3 (v_cmp_gt_u64 + cndmask).
#define INS(K) do {                                         \
    u64 _t = (K), _m;                                       \
    _m = _t > a0 ? _t : a0; _t = _t > a0 ? a0 : _t; a0 = _m;\
    _m = _t > a1 ? _t : a1; _t = _t > a1 ? a1 : _t; a1 = _m;\
    _m = _t > a2 ? _t : a2; _t = _t > a2 ? a2 : _t; a2 = _m;\
    a3 = _t > a3 ? _t : a3;                                 \
  } while (0)

__global__ __launch_bounds__(512) void seg_top4_v2(
    const int* __restrict__ rp,
    const float* __restrict__ esc,
    float4* __restrict__ out_v,
    float4* __restrict__ out_i,
    int nseg)
{
  const int lane = threadIdx.x & 63;
  const int g    = lane >> 4;
  const int t    = lane & 15;
  const int w    = (int)((blockIdx.x * (unsigned)blockDim.x + threadIdx.x) >> 6);
  const int seg  = (w << 2) + g;
  if (seg >= nseg) return;

  const int lo  = rp[seg];
  const int hi  = rp[seg + 1];
  const int deg = hi - lo;

  u64 a0 = 0, a1 = 0, a2 = 0, a3 = 0;   // sentinels < any real key

  // head: 0..3 elements up to the first 16B-aligned index
  const int head = ((lo + 3) & ~3) - lo;
  if (t < head) {
    const int p = lo + t;
    if (p < hi) INS(mkkey(esc[p], p));
  }

  // main: aligned float4 per lane, 64 elements per group-iteration
  int p = lo + head + (t << 2);
  for (; p + 3 < hi; p += 64) {
    const float4 f = *reinterpret_cast<const float4*>(esc + p);
    INS(mkkey(f.x, p));
    INS(mkkey(f.y, p + 1));
    INS(mkkey(f.z, p + 2));
    INS(mkkey(f.w, p + 3));
  }

  // tail: the single straddling lane handles <=3 scalars
  if (p < hi)     INS(mkkey(esc[p], p));
  if (p + 1 < hi) INS(mkkey(esc[p + 1], p + 1));
  if (p + 2 < hi) INS(mkkey(esc[p + 2], p + 2));

  // 4-stage butterfly bitonic merge across the 16-lane group
  #pragma unroll
  for (int m = 1; m <= 8; m <<= 1) {
    const u64 p0 = bfly(a0, m);
    const u64 p1 = bfly(a1, m);
    const u64 p2 = bfly(a2, m);
    const u64 p3 = bfly(a3, m);
    a0 = (a0 > p3) ? a0 : p3;          // keep top-4 of the bitonic 8
    a1 = (a1 > p2) ? a1 : p2;
    a2 = (a2 > p1) ? a2 : p1;
    a3 = (a3 > p0) ? a3 : p0;
    u64 s;
    if (a2 > a0) { s = a0; a0 = a2; a2 = s; }   // 4-elem bitonic resort (desc)
    if (a3 > a1) { s = a1; a1 = a3; a3 = s; }
    if (a1 > a0) { s = a0; a0 = a1; a1 = s; }
    if (a3 > a2) { s = a2; a2 = a3; a3 = s; }
  }

  if (t == 0) {
    const u64 ks[4] = { a0, a1, a2, a3 };
    float v[4], ix[4];
    #pragma unroll
    for (int j = 0; j < 4; ++j) {
      if (j < deg) {
        const uint32_t m = (uint32_t)(ks[j] >> 32);
        const uint32_t u = m ^ ((m & 0x80000000u) ? 0x80000000u : 0xFFFFFFFFu);
        v[j]  = __uint_as_float(u);                    // exact input f32 score
        ix[j] = (float)(int)(~(uint32_t)(ks[j] & 0xFFFFFFFFull));
      } else {
        v[j]  = -1.0e38f;   // bf16-FINITE pad — never anything >= 3.39e38
        ix[j] = -1.0f;
      }
    }
    out_v[seg] = make_float4(v[0], v[1], v[2], v[3]);
    out_i[seg] = make_float4(ix[0], ix[1], ix[2], ix[3]);
  }
}

extern "C" void kernel_launch(void* const* d_in, const int* in_sizes, int n_in,
                              void* d_out, int out_size, void* d_ws, size_t ws_size,
                              hipStream_t stream) {
  const int*   rp  = (const int*)d_in[0];    // row_ptr [N+1]
  const float* esc = (const float*)d_in[1];  // edge_scores [E]
  const int   nseg = in_sizes[0] - 1;

  float4* out_v = (float4*)d_out;                                  // vals [N]
  float4* out_i = (float4*)((float*)d_out + (size_t)nseg * 4);     // idx  [N]

  const int waves = (nseg + 3) >> 2;          // 4 segments per wave
  const int wpb   = 8;                        // 512 threads per block
  const int grid  = (waves + wpb - 1) / wpb;
  seg_top4_v2<<<grid, 512, 0, stream>>>(rp, esc, out_v, out_i, nseg);
}

// Round 8
// 88.677 us; speedup vs baseline: 1.3998x; 1.3998x over previous
//
#include <hip/hip_runtime.h>
#include <stdint.h>

// Segmented top-4 over CSR (N=500K segments, E=32M edges).
// d_out = f32: [N*4 topk_vals][N*4 topk_idx-as-float], 16 MB.
// Pads MUST be bf16-finite (checker compares in bf16; -inf pad => nan).
//
// One 64-lane wave = 4 segments x 16 lanes. Per-lane branchless sorted top-4
// of (val,idx) pairs over a clamped+masked strided scan; then a 4-round DPP
// extract-max merge (no LDS, no shfl): per round, 16-lane max-reduce of head
// vals + min-reduce of idx among ties (stable, globally unique idx), then pop
// exactly the winning (val,idx). Matches jnp.lexsort((-scores, seg)) exactly.

template <int CTRL>
__device__ __forceinline__ float dppf(float x) {
  int s = __float_as_int(x);
  int t = __builtin_amdgcn_update_dpp(s, s, CTRL, 0xF, 0xF, false);
  return __int_as_float(t);
}
template <int CTRL>
__device__ __forceinline__ int dppi(int x) {
  return __builtin_amdgcn_update_dpp(x, x, CTRL, 0xF, 0xF, false);
}

// 16-lane (row) reductions: quad_perm xor1 (0xB1), xor2 (0x4E),
// row_half_mirror (0x141), row_mirror (0x140). All stay within the 16-lane
// row => never read lanes of other groups (safe with partial last wave).
__device__ __forceinline__ float grpmax16(float x) {
  x = fmaxf(x, dppf<0xB1>(x));
  x = fmaxf(x, dppf<0x4E>(x));
  x = fmaxf(x, dppf<0x141>(x));
  x = fmaxf(x, dppf<0x140>(x));
  return x;
}
__device__ __forceinline__ int grpmin16(int x) {
  x = min(x, dppi<0xB1>(x));
  x = min(x, dppi<0x4E>(x));
  x = min(x, dppi<0x141>(x));
  x = min(x, dppi<0x140>(x));
  return x;
}

__global__ __launch_bounds__(512) void seg_top4_v3(
    const int* __restrict__ rp,
    const float* __restrict__ esc,
    float4* __restrict__ out_v,
    float4* __restrict__ out_i,
    int nseg, int E)
{
  const int lane = threadIdx.x & 63;
  const int g    = lane >> 4;          // group (segment slot) within wave
  const int t    = lane & 15;          // lane within 16-lane group
  const int w    = (int)((blockIdx.x * (unsigned)blockDim.x + threadIdx.x) >> 6);
  const int seg  = (w << 2) + g;
  if (seg >= nseg) return;             // whole groups drop out; rows intact

  const int lo  = rp[seg];
  const int hi  = rp[seg + 1];
  const int deg = hi - lo;

  const float NEG = __int_as_float(0xFF800000u);   // -inf sentinel
  float av0 = NEG, av1 = NEG, av2 = NEG, av3 = NEG;
  int   ai0 = -1,  ai1 = -1,  ai2 = -1,  ai3 = -1;

  // ---- scan: 4 elems/lane/iter, clamped loads + -inf masking -------------
  int base = lo + (t << 2);
  while (__any(base < hi)) {
    #pragma unroll
    for (int j = 0; j < 4; ++j) {
      const int e  = base + j;
      const int ec = min(e, E - 1);          // always in-bounds [0,E)
      float v = esc[ec];
      v = (e < hi) ? v : NEG;                // masked elems never insert
      // branchless sorted insert of (v,e); stable (strict >, ascending e)
      const bool c0 = v > av0;
      float d0v = c0 ? av0 : v;  int d0i = c0 ? ai0 : e;
      av0 = c0 ? v : av0;        ai0 = c0 ? e : ai0;
      const bool c1 = d0v > av1;
      float d1v = c1 ? av1 : d0v; int d1i = c1 ? ai1 : d0i;
      av1 = c1 ? d0v : av1;       ai1 = c1 ? d0i : ai1;
      const bool c2 = d1v > av2;
      float d2v = c2 ? av2 : d1v; int d2i = c2 ? ai2 : d1i;
      av2 = c2 ? d1v : av2;       ai2 = c2 ? d1i : ai2;
      const bool c3 = d2v > av3;
      av3 = c3 ? d2v : av3;       ai3 = c3 ? d2i : ai3;
    }
    base += 64;
  }

  // ---- merge: 4 rounds of DPP extract-max with exact-one pop -------------
  float rv0, rv1, rv2, rv3;
  int   ri0, ri1, ri2, ri3;
  #pragma unroll
  for (int r = 0; r < 4; ++r) {
    const float M = grpmax16(av0);
    const int   c = (av0 == M) ? ai0 : 0x7FFFFFFF;
    const int   W = grpmin16(c);             // stable: min original idx wins
    if (r == 0) { rv0 = M; ri0 = W; }
    else if (r == 1) { rv1 = M; ri1 = W; }
    else if (r == 2) { rv2 = M; ri2 = W; }
    else { rv3 = M; ri3 = W; }
    if (r < 3) {
      const bool p = (av0 == M) && (ai0 == W);   // exactly one lane pops
      av0 = p ? av1 : av0; ai0 = p ? ai1 : ai0;
      av1 = p ? av2 : av1; ai1 = p ? ai2 : ai1;
      av2 = p ? av3 : av2; ai2 = p ? ai3 : ai2;
      // av3 left stale: a lane pops at most 3 times before round 3 reads av0
    }
  }

  // ---- epilogue: lane 0 of each group writes two float4 ------------------
  if (t == 0) {
    float4 vv, ii;
    vv.x = (0 < deg) ? rv0 : -1.0e38f;  ii.x = (0 < deg) ? (float)ri0 : -1.0f;
    vv.y = (1 < deg) ? rv1 : -1.0e38f;  ii.y = (1 < deg) ? (float)ri1 : -1.0f;
    vv.z = (2 < deg) ? rv2 : -1.0e38f;  ii.z = (2 < deg) ? (float)ri2 : -1.0f;
    vv.w = (3 < deg) ? rv3 : -1.0e38f;  ii.w = (3 < deg) ? (float)ri3 : -1.0f;
    out_v[seg] = vv;     // pads stay bf16-finite: -1.0e38f -> bf16 0xFF16
    out_i[seg] = ii;
  }
}

extern "C" void kernel_launch(void* const* d_in, const int* in_sizes, int n_in,
                              void* d_out, int out_size, void* d_ws, size_t ws_size,
                              hipStream_t stream) {
  const int*   rp  = (const int*)d_in[0];    // row_ptr [N+1]
  const float* esc = (const float*)d_in[1];  // edge_scores [E]
  const int   nseg = in_sizes[0] - 1;
  const int   E    = in_sizes[1];

  float4* out_v = (float4*)d_out;                                  // vals [N]
  float4* out_i = (float4*)((float*)d_out + (size_t)nseg * 4);     // idx  [N]

  const int waves = (nseg + 3) >> 2;          // 4 segments per wave
  const int wpb   = 8;                        // 512 threads per block
  const int grid  = (waves + wpb - 1) / wpb;
  seg_top4_v3<<<grid, 512, 0, stream>>>(rp, esc, out_v, out_i, nseg, E);
}

// Round 9
// 79.712 us; speedup vs baseline: 1.5573x; 1.1125x over previous
//
#include <hip/hip_runtime.h>
#include <stdint.h>

// Segmented top-4 over CSR (N=500K segments, E=32M edges).
// d_out = f32: [N*4 topk_vals][N*4 topk_idx-as-float], 16 MB.
// Pads MUST be bf16-finite (checker compares in bf16; -inf pad => nan).
//
// One 64-lane wave = 4 segments x 16 lanes. Scan: aligned float4 per lane
// (64 elems per group-iteration), branch-free range mask, and a
// v_med3_f32-based sorted-quad insert (4 inst for values + cmp/cndmask for
// indices). Merge: 4 rounds of DPP extract-max with min-idx tie-break
// (stable; == jnp.lexsort((-scores, seg))). Lane 0 packs two float4 stores.

template <int CTRL>
__device__ __forceinline__ float dppf(float x) {
  int r = __builtin_amdgcn_update_dpp(__float_as_int(x), __float_as_int(x),
                                      CTRL, 0xF, 0xF, false);
  return __int_as_float(r);
}
template <int CTRL>
__device__ __forceinline__ int dppi(int x) {
  return __builtin_amdgcn_update_dpp(x, x, CTRL, 0xF, 0xF, false);
}

// 16-lane reductions: quad_perm xor1 (0xB1), xor2 (0x4E), row_half_mirror
// (0x141), row_mirror (0x140) — all stay inside the 16-lane row.
__device__ __forceinline__ float grpmax16(float x) {
  x = fmaxf(x, dppf<0xB1>(x));
  x = fmaxf(x, dppf<0x4E>(x));
  x = fmaxf(x, dppf<0x141>(x));
  x = fmaxf(x, dppf<0x140>(x));
  return x;
}
__device__ __forceinline__ int grpmin16(int x) {
  x = min(x, dppi<0xB1>(x));
  x = min(x, dppi<0x4E>(x));
  x = min(x, dppi<0x141>(x));
  x = min(x, dppi<0x140>(x));
  return x;
}

__global__ __launch_bounds__(512) void seg_top4_v4(
    const int* __restrict__ rp,
    const float* __restrict__ esc,
    float4* __restrict__ out_v,
    float4* __restrict__ out_i,
    int nseg, int E)
{
  const int lane = threadIdx.x & 63;
  const int g    = lane >> 4;          // group (segment slot) within wave
  const int t    = lane & 15;          // lane within 16-lane group
  const int w    = (int)((blockIdx.x * (unsigned)blockDim.x + threadIdx.x) >> 6);
  const int seg  = (w << 2) + g;
  if (seg >= nseg) return;             // never fires (N % 4 == 0), safety only

  const int lo  = rp[seg];
  const int hi  = rp[seg + 1];
  const int deg = hi - lo;             // group-uniform

  const float NEG = __int_as_float(0xFF800000u);   // -inf sentinel
  float av0 = NEG, av1 = NEG, av2 = NEG, av3 = NEG;
  int   ai0 = -1,  ai1 = -1,  ai2 = -1,  ai3 = -1;

  // med3 sorted-quad insert: values 4 inst, indices via masks on OLD vals.
#define INS4(V, EIDX) do {                                       \
    const float _v = (V); const int _e = (EIDX);                 \
    const bool c0 = _v > av0;                                    \
    const bool c1 = _v > av1;                                    \
    const bool c2 = _v > av2;                                    \
    const bool c3 = _v > av3;                                    \
    const int n0 = c0 ? _e  : ai0;                               \
    const int n1 = c0 ? ai0 : (c1 ? _e : ai1);                   \
    const int n2 = c1 ? ai1 : (c2 ? _e : ai2);                   \
    const int n3 = c2 ? ai2 : (c3 ? _e : ai3);                   \
    const float m1 = __builtin_amdgcn_fmed3f(_v, av0, av1);      \
    const float m2 = __builtin_amdgcn_fmed3f(_v, av1, av2);      \
    const float m3 = __builtin_amdgcn_fmed3f(_v, av2, av3);      \
    av0 = fmaxf(av0, _v);                                        \
    av1 = m1; av2 = m2; av3 = m3;                                \
    ai0 = n0; ai1 = n1; ai2 = n2; ai3 = n3;                      \
  } while (0)

  // ---- scan: aligned float4 window, 64 elems per group-iteration ---------
  int qs  = (lo & ~3) + (t << 2);      // 4-aligned quad start for this lane
  int rel = qs - lo;                   // offset within segment (may be <0)

  while (__any(qs < hi)) {
    const int qc = min(qs, E - 4);     // stays 4-aligned; E % 4 == 0
    const float4 f = *reinterpret_cast<const float4*>(esc + qc);
    // elem j valid iff 0 <= rel+j < deg  (unsigned wrap handles rel<0)
    const float v0 = ((unsigned)(rel + 0) < (unsigned)deg) ? f.x : NEG;
    const float v1 = ((unsigned)(rel + 1) < (unsigned)deg) ? f.y : NEG;
    const float v2 = ((unsigned)(rel + 2) < (unsigned)deg) ? f.z : NEG;
    const float v3 = ((unsigned)(rel + 3) < (unsigned)deg) ? f.w : NEG;
    INS4(v0, qs + 0);
    INS4(v1, qs + 1);
    INS4(v2, qs + 2);
    INS4(v3, qs + 3);
    qs  += 64;
    rel += 64;
  }
#undef INS4

  // ---- merge: 4 rounds of DPP extract-max with exact-one pop -------------
  float rv0, rv1, rv2, rv3;
  int   ri0, ri1, ri2, ri3;
  #pragma unroll
  for (int r = 0; r < 4; ++r) {
    const float M = grpmax16(av0);
    const int   c = (av0 == M) ? ai0 : 0x7FFFFFFF;
    const int   W = grpmin16(c);             // stable: min original idx wins
    if (r == 0)      { rv0 = M; ri0 = W; }
    else if (r == 1) { rv1 = M; ri1 = W; }
    else if (r == 2) { rv2 = M; ri2 = W; }
    else             { rv3 = M; ri3 = W; }
    if (r < 3) {
      const bool p = (av0 == M) && (ai0 == W);   // exactly one lane pops
      av0 = p ? av1 : av0; ai0 = p ? ai1 : ai0;
      av1 = p ? av2 : av1; ai1 = p ? ai2 : ai1;
      av2 = p ? av3 : av2; ai2 = p ? ai3 : ai2;
      // av3 left stale: a lane pops at most 3 times before round 3 reads av0
    }
  }

  // ---- epilogue: lane 0 of each group writes two float4 ------------------
  if (t == 0) {
    float4 vv, ii;
    vv.x = (0 < deg) ? rv0 : -1.0e38f;  ii.x = (0 < deg) ? (float)ri0 : -1.0f;
    vv.y = (1 < deg) ? rv1 : -1.0e38f;  ii.y = (1 < deg) ? (float)ri1 : -1.0f;
    vv.z = (2 < deg) ? rv2 : -1.0e38f;  ii.z = (2 < deg) ? (float)ri2 : -1.0f;
    vv.w = (3 < deg) ? rv3 : -1.0e38f;  ii.w = (3 < deg) ? (float)ri3 : -1.0f;
    out_v[seg] = vv;     // pads stay bf16-finite: -1.0e38f -> bf16 0xFF16
    out_i[seg] = ii;
  }
}

extern "C" void kernel_launch(void* const* d_in, const int* in_sizes, int n_in,
                              void* d_out, int out_size, void* d_ws, size_t ws_size,
                              hipStream_t stream) {
  const int*   rp  = (const int*)d_in[0];    // row_ptr [N+1]
  const float* esc = (const float*)d_in[1];  // edge_scores [E]
  const int   nseg = in_sizes[0] - 1;
  const int   E    = in_sizes[1];

  float4* out_v = (float4*)d_out;                                  // vals [N]
  float4* out_i = (float4*)((float*)d_out + (size_t)nseg * 4);     // idx  [N]

  const int waves = (nseg + 3) >> 2;          // 4 segments per wave
  const int wpb   = 8;                        // 512 threads per block
  const int grid  = (waves + wpb - 1) / wpb;
  seg_top4_v4<<<grid, 512, 0, stream>>>(rp, esc, out_v, out_i, nseg, E);
}

// Round 10
// 79.558 us; speedup vs baseline: 1.5603x; 1.0019x over previous
//
#include <hip/hip_runtime.h>
#include <stdint.h>

// Segmented top-4 over CSR (N=500K segments, E=32M edges).
// d_out = f32: [N*4 topk_vals][N*4 topk_idx-as-float], 16 MB.
// Pads MUST be bf16-finite (checker compares in bf16; -inf pad => nan).
//
// One 64-lane wave = 4 segments x 16 lanes. Scan: aligned float4 per lane
// (64 elems per group-iteration), SOFTWARE-PIPELINED (prefetch next quad
// before processing current — load->use distance ~160+ issued cycles),
// branch-free range mask, v_med3_f32 sorted-quad insert. Merge: 4 rounds of
// DPP extract-max with min-idx tie-break (stable; == lexsort((-s, seg))).

template <int CTRL>
__device__ __forceinline__ float dppf(float x) {
  int r = __builtin_amdgcn_update_dpp(__float_as_int(x), __float_as_int(x),
                                      CTRL, 0xF, 0xF, false);
  return __int_as_float(r);
}
template <int CTRL>
__device__ __forceinline__ int dppi(int x) {
  return __builtin_amdgcn_update_dpp(x, x, CTRL, 0xF, 0xF, false);
}

// 16-lane reductions: quad_perm xor1 (0xB1), xor2 (0x4E), row_half_mirror
// (0x141), row_mirror (0x140) — all stay inside the 16-lane row.
__device__ __forceinline__ float grpmax16(float x) {
  x = fmaxf(x, dppf<0xB1>(x));
  x = fmaxf(x, dppf<0x4E>(x));
  x = fmaxf(x, dppf<0x141>(x));
  x = fmaxf(x, dppf<0x140>(x));
  return x;
}
__device__ __forceinline__ int grpmin16(int x) {
  x = min(x, dppi<0xB1>(x));
  x = min(x, dppi<0x4E>(x));
  x = min(x, dppi<0x141>(x));
  x = min(x, dppi<0x140>(x));
  return x;
}

__global__ __launch_bounds__(512) void seg_top4_v5(
    const int* __restrict__ rp,
    const float* __restrict__ esc,
    float4* __restrict__ out_v,
    float4* __restrict__ out_i,
    int nseg, int E)
{
  const int lane = threadIdx.x & 63;
  const int g    = lane >> 4;          // group (segment slot) within wave
  const int t    = lane & 15;          // lane within 16-lane group
  const int w    = (int)((blockIdx.x * (unsigned)blockDim.x + threadIdx.x) >> 6);
  const int seg  = (w << 2) + g;
  if (seg >= nseg) return;             // never fires (N % 4 == 0), safety only

  const int lo  = rp[seg];
  const int hi  = rp[seg + 1];
  const int deg = hi - lo;             // group-uniform

  const float NEG = __int_as_float(0xFF800000u);   // -inf sentinel
  float av0 = NEG, av1 = NEG, av2 = NEG, av3 = NEG;
  int   ai0 = -1,  ai1 = -1,  ai2 = -1,  ai3 = -1;

  // med3 sorted-quad insert: values 4 inst, indices via masks on OLD vals.
#define INS4(V, EIDX) do {                                       \
    const float _v = (V); const int _e = (EIDX);                 \
    const bool c0 = _v > av0;                                    \
    const bool c1 = _v > av1;                                    \
    const bool c2 = _v > av2;                                    \
    const bool c3 = _v > av3;                                    \
    const int n0 = c0 ? _e  : ai0;                               \
    const int n1 = c0 ? ai0 : (c1 ? _e : ai1);                   \
    const int n2 = c1 ? ai1 : (c2 ? _e : ai2);                   \
    const int n3 = c2 ? ai2 : (c3 ? _e : ai3);                   \
    const float m1 = __builtin_amdgcn_fmed3f(_v, av0, av1);      \
    const float m2 = __builtin_amdgcn_fmed3f(_v, av1, av2);      \
    const float m3 = __builtin_amdgcn_fmed3f(_v, av2, av3);      \
    av0 = fmaxf(av0, _v);                                        \
    av1 = m1; av2 = m2; av3 = m3;                                \
    ai0 = n0; ai1 = n1; ai2 = n2; ai3 = n3;                      \
  } while (0)

  // ---- scan: pipelined aligned float4 window, 64 elems/group-iter --------
  const int Eclamp = E - 4;            // 4-aligned (E % 4 == 0)
  int qs  = (lo & ~3) + (t << 2);      // 4-aligned quad start for this lane
  int rel = qs - lo;                   // offset within segment (may be <0)

  float4 f = *reinterpret_cast<const float4*>(esc + min(qs, Eclamp));

  while (__any(qs < hi)) {
    // prefetch next quad first: load->use distance spans the 4 INS4 below
    const float4 fn =
        *reinterpret_cast<const float4*>(esc + min(qs + 64, Eclamp));

    // elem j valid iff 0 <= rel+j < deg  (unsigned wrap handles rel<0)
    const float v0 = ((unsigned)(rel + 0) < (unsigned)deg) ? f.x : NEG;
    const float v1 = ((unsigned)(rel + 1) < (unsigned)deg) ? f.y : NEG;
    const float v2 = ((unsigned)(rel + 2) < (unsigned)deg) ? f.z : NEG;
    const float v3 = ((unsigned)(rel + 3) < (unsigned)deg) ? f.w : NEG;
    INS4(v0, qs + 0);
    INS4(v1, qs + 1);
    INS4(v2, qs + 2);
    INS4(v3, qs + 3);

    f = fn;
    qs  += 64;
    rel += 64;
  }
#undef INS4

  // ---- merge: 4 rounds of DPP extract-max with exact-one pop -------------
  float rv0, rv1, rv2, rv3;
  int   ri0, ri1, ri2, ri3;
  #pragma unroll
  for (int r = 0; r < 4; ++r) {
    const float M = grpmax16(av0);
    const int   c = (av0 == M) ? ai0 : 0x7FFFFFFF;
    const int   W = grpmin16(c);             // stable: min original idx wins
    if (r == 0)      { rv0 = M; ri0 = W; }
    else if (r == 1) { rv1 = M; ri1 = W; }
    else if (r == 2) { rv2 = M; ri2 = W; }
    else             { rv3 = M; ri3 = W; }
    if (r < 3) {
      const bool p = (av0 == M) && (ai0 == W);   // exactly one lane pops
      av0 = p ? av1 : av0; ai0 = p ? ai1 : ai0;
      av1 = p ? av2 : av1; ai1 = p ? ai2 : ai1;
      av2 = p ? av3 : av2; ai2 = p ? ai3 : ai2;
      // av3 left stale: a lane pops at most 3 times before round 3 reads av0
    }
  }

  // ---- epilogue: lane 0 of each group writes two float4 ------------------
  if (t == 0) {
    float4 vv, ii;
    vv.x = (0 < deg) ? rv0 : -1.0e38f;  ii.x = (0 < deg) ? (float)ri0 : -1.0f;
    vv.y = (1 < deg) ? rv1 : -1.0e38f;  ii.y = (1 < deg) ? (float)ri1 : -1.0f;
    vv.z = (2 < deg) ? rv2 : -1.0e38f;  ii.z = (2 < deg) ? (float)ri2 : -1.0f;
    vv.w = (3 < deg) ? rv3 : -1.0e38f;  ii.w = (3 < deg) ? (float)ri3 : -1.0f;
    out_v[seg] = vv;     // pads stay bf16-finite: -1.0e38f -> bf16 0xFF16
    out_i[seg] = ii;
  }
}

extern "C" void kernel_launch(void* const* d_in, const int* in_sizes, int n_in,
                              void* d_out, int out_size, void* d_ws, size_t ws_size,
                              hipStream_t stream) {
  const int*   rp  = (const int*)d_in[0];    // row_ptr [N+1]
  const float* esc = (const float*)d_in[1];  // edge_scores [E]
  const int   nseg = in_sizes[0] - 1;
  const int   E    = in_sizes[1];

  float4* out_v = (float4*)d_out;                                  // vals [N]
  float4* out_i = (float4*)((float*)d_out + (size_t)nseg * 4);     // idx  [N]

  const int waves = (nseg + 3) >> 2;          // 4 segments per wave
  const int wpb   = 8;                        // 512 threads per block
  const int grid  = (waves + wpb - 1) / wpb;
  seg_top4_v5<<<grid, 512, 0, stream>>>(rp, esc, out_v, out_i, nseg, E);
}

// Round 11
// 77.414 us; speedup vs baseline: 1.6035x; 1.0277x over previous
//
#include <hip/hip_runtime.h>
#include <stdint.h>

// Segmented top-4 over CSR (N=500K segments, E=32M edges).
// d_out = f32: [N*4 topk_vals][N*4 topk_idx-as-float], 16 MB.
// Pads MUST be bf16-finite (checker compares in bf16; -inf pad => nan).
//
// v6: one 64-lane wave = 8 segments x 8 lanes (merge fixed-cost halved vs
// 16-lane groups; scan quantum 32 elems/group-iter cuts max-of-group waste).
// Scan: aligned float4 per lane, depth-2 rotating prefetch, branch-free
// range mask, v_med3_f32 sorted-quad insert. Merge: 4 rounds of 8-lane DPP
// extract-max with min-idx tie-break (stable == jnp.lexsort((-s, seg))).

template <int CTRL>
__device__ __forceinline__ float dppf(float x) {
  int r = __builtin_amdgcn_update_dpp(__float_as_int(x), __float_as_int(x),
                                      CTRL, 0xF, 0xF, false);
  return __int_as_float(r);
}
template <int CTRL>
__device__ __forceinline__ int dppi(int x) {
  return __builtin_amdgcn_update_dpp(x, x, CTRL, 0xF, 0xF, false);
}

// 8-lane reductions: quad_perm xor1 (0xB1), xor2 (0x4E), row_half_mirror
// (0x141: lane i <-> 7-i within each 8) — all stay inside the 8-lane group.
__device__ __forceinline__ float grpmax8(float x) {
  x = fmaxf(x, dppf<0xB1>(x));
  x = fmaxf(x, dppf<0x4E>(x));
  x = fmaxf(x, dppf<0x141>(x));
  return x;
}
__device__ __forceinline__ int grpmin8(int x) {
  x = min(x, dppi<0xB1>(x));
  x = min(x, dppi<0x4E>(x));
  x = min(x, dppi<0x141>(x));
  return x;
}

__global__ __launch_bounds__(256) void seg_top4_v6(
    const int* __restrict__ rp,
    const float* __restrict__ esc,
    float4* __restrict__ out_v,
    float4* __restrict__ out_i,
    int nseg, int E)
{
  const int lane = threadIdx.x & 63;
  const int g    = lane >> 3;          // group (segment slot) within wave: 0..7
  const int t    = lane & 7;           // lane within 8-lane group
  const int w    = (int)((blockIdx.x * (unsigned)blockDim.x + threadIdx.x) >> 6);
  const int seg  = (w << 3) + g;
  if (seg >= nseg) return;             // never fires (N % 8 == 0), safety only

  const int lo  = rp[seg];
  const int hi  = rp[seg + 1];
  const int deg = hi - lo;             // group-uniform

  const float NEG = __int_as_float(0xFF800000u);   // -inf sentinel
  float av0 = NEG, av1 = NEG, av2 = NEG, av3 = NEG;
  int   ai0 = -1,  ai1 = -1,  ai2 = -1,  ai3 = -1;

  // med3 sorted-quad insert: values 4 inst, indices via masks on OLD vals.
#define INS4(V, EIDX) do {                                       \
    const float _v = (V); const int _e = (EIDX);                 \
    const bool c0 = _v > av0;                                    \
    const bool c1 = _v > av1;                                    \
    const bool c2 = _v > av2;                                    \
    const bool c3 = _v > av3;                                    \
    const int n0 = c0 ? _e  : ai0;                               \
    const int n1 = c0 ? ai0 : (c1 ? _e : ai1);                   \
    const int n2 = c1 ? ai1 : (c2 ? _e : ai2);                   \
    const int n3 = c2 ? ai2 : (c3 ? _e : ai3);                   \
    const float m1 = __builtin_amdgcn_fmed3f(_v, av0, av1);      \
    const float m2 = __builtin_amdgcn_fmed3f(_v, av1, av2);      \
    const float m3 = __builtin_amdgcn_fmed3f(_v, av2, av3);      \
    av0 = fmaxf(av0, _v);                                        \
    av1 = m1; av2 = m2; av3 = m3;                                \
    ai0 = n0; ai1 = n1; ai2 = n2; ai3 = n3;                      \
  } while (0)

#define PROC(F, QS, REL) do {                                            \
    const float v0 = ((unsigned)((REL) + 0) < (unsigned)deg) ? (F).x : NEG; \
    const float v1 = ((unsigned)((REL) + 1) < (unsigned)deg) ? (F).y : NEG; \
    const float v2 = ((unsigned)((REL) + 2) < (unsigned)deg) ? (F).z : NEG; \
    const float v3 = ((unsigned)((REL) + 3) < (unsigned)deg) ? (F).w : NEG; \
    INS4(v0, (QS) + 0);                                                  \
    INS4(v1, (QS) + 1);                                                  \
    INS4(v2, (QS) + 2);                                                  \
    INS4(v3, (QS) + 3);                                                  \
  } while (0)

  // ---- scan: depth-2 pipelined aligned float4, 32 elems/group-iter -------
  const int Ec = E - 4;                // 4-aligned (E % 4 == 0)
  int qs  = (lo & ~3) + (t << 2);      // 4-aligned quad start for this lane
  int rel = qs - lo;                   // offset within segment (may be <0)

  float4 f  = *reinterpret_cast<const float4*>(esc + min(qs, Ec));
  float4 fn = *reinterpret_cast<const float4*>(esc + min(qs + 32, Ec));

  while (__any(qs < hi)) {
    const float4 fnn =
        *reinterpret_cast<const float4*>(esc + min(qs + 64, Ec));
    PROC(f, qs, rel);
    f = fn; fn = fnn;
    qs  += 32;
    rel += 32;
  }
#undef PROC
#undef INS4

  // ---- merge: 4 rounds of 8-lane DPP extract-max, min-idx tie-break ------
  float rv0, rv1, rv2, rv3;
  int   ri0, ri1, ri2, ri3;
  #pragma unroll
  for (int r = 0; r < 4; ++r) {
    const float M = grpmax8(av0);
    const int   c = (av0 == M) ? ai0 : 0x7FFFFFFF;
    const int   W = grpmin8(c);              // stable: min original idx wins
    if (r == 0)      { rv0 = M; ri0 = W; }
    else if (r == 1) { rv1 = M; ri1 = W; }
    else if (r == 2) { rv2 = M; ri2 = W; }
    else             { rv3 = M; ri3 = W; }
    if (r < 3) {
      const bool p = (c == W);   // exactly the winning lane (W < INT_MAX
                                 // only where av0==M and ai0==W; unique idx)
      av0 = p ? av1 : av0; ai0 = p ? ai1 : ai0;
      av1 = p ? av2 : av1; ai1 = p ? ai2 : ai1;
      av2 = p ? av3 : av2; ai2 = p ? ai3 : ai2;
      // av3 left stale: a lane pops at most 3 times before round 3 reads av0
    }
  }

  // ---- epilogue: lane 0 of each group writes two float4 ------------------
  if (t == 0) {
    float4 vv, ii;
    vv.x = (0 < deg) ? rv0 : -1.0e38f;  ii.x = (0 < deg) ? (float)ri0 : -1.0f;
    vv.y = (1 < deg) ? rv1 : -1.0e38f;  ii.y = (1 < deg) ? (float)ri1 : -1.0f;
    vv.z = (2 < deg) ? rv2 : -1.0e38f;  ii.z = (2 < deg) ? (float)ri2 : -1.0f;
    vv.w = (3 < deg) ? rv3 : -1.0e38f;  ii.w = (3 < deg) ? (float)ri3 : -1.0f;
    out_v[seg] = vv;     // pads stay bf16-finite: -1.0e38f -> bf16 0xFF16
    out_i[seg] = ii;
  }
}

extern "C" void kernel_launch(void* const* d_in, const int* in_sizes, int n_in,
                              void* d_out, int out_size, void* d_ws, size_t ws_size,
                              hipStream_t stream) {
  const int*   rp  = (const int*)d_in[0];    // row_ptr [N+1]
  const float* esc = (const float*)d_in[1];  // edge_scores [E]
  const int   nseg = in_sizes[0] - 1;
  const int   E    = in_sizes[1];

  float4* out_v = (float4*)d_out;                                  // vals [N]
  float4* out_i = (float4*)((float*)d_out + (size_t)nseg * 4);     // idx  [N]

  // 256 threads = 4 waves = 32 segments per block
  const int segs_per_block = 32;
  const int grid = (nseg + segs_per_block - 1) / segs_per_block;
  seg_top4_v6<<<grid, 256, 0, stream>>>(rp, esc, out_v, out_i, nseg, E);
}